// Round 3
// baseline (125.646 us; speedup 1.0000x reference)
//
#include <hip/hip_runtime.h>
#include <math.h>

namespace {

constexpr int Hh = 112, Ww = 112, Cc = 64, Nn = 16;
constexpr int OHh = 56, OWw = 56;
constexpr int HW = Hh * Ww;            // 12544
constexpr int OP = OHh * OWw;          // 3136 positions per n
constexpr int NP = Nn * OP;            // 50176 positions total
constexpr float BN_EPS_F = 1e-5f;
constexpr float CLAMP_MIN_F = 1e-4f;
constexpr int TP = 24;                 // LDS tile pitch (rows stride 24 -> perfect 2-way banks)
constexpr int TILE_ELEMS = 18 * 18;    // 324 spatial elems per channel tile

__device__ __forceinline__ int reflect_idx(int t) {
    t = t < 0 ? -t : t;
    t = (t >= Hh) ? (2 * Hh - 2 - t) : t;
    return t;
}

// ---------------- K1: full-res conv (64ch -> 9 taps), stats + raw sigma at even pos.
// 2 channels per barrier; ds_write consumes regs loaded a full iteration earlier.
__global__ __launch_bounds__(256) void conv_stats_sig_kernel(
    const float* __restrict__ x, const float* __restrict__ wgt,
    double* __restrict__ stats, float* __restrict__ sig_raw /* [9][NP] */)
{
    __shared__ float tile[2][2][18 * TP];
    __shared__ float red_sum[4][9];
    __shared__ float red_sq[4][9];

    const int tid = threadIdx.x;
    const int tx = tid & 15, ty = tid >> 4;
    const int n = blockIdx.y;
    const int h0 = (int)(blockIdx.x / 7) * 16;
    const int w0 = (int)(blockIdx.x % 7) * 16;

    // spatial load mapping (fixed per block)
    const int i0 = tid, i1 = tid + 256;
    const bool v1 = (i1 < TILE_ELEMS);
    int l0, g0, l1 = 0, g1 = 0;
    {
        const int r = i0 / 18, cl = i0 - r * 18;
        l0 = r * TP + cl;
        g0 = reflect_idx(h0 - 1 + r) * Ww + reflect_idx(w0 - 1 + cl);
    }
    if (v1) {
        const int r = i1 / 18, cl = i1 - r * 18;
        l1 = r * TP + cl;
        g1 = reflect_idx(h0 - 1 + r) * Ww + reflect_idx(w0 - 1 + cl);
    }

    const float* xb = x + (size_t)n * Cc * HW;

    // prologue: pair 0 (channels 0,1) loaded and written; pair 1 in flight
    float a0 = xb[g0], b0 = xb[HW + g0];
    float a1 = 0.f, b1 = 0.f;
    if (v1) { a1 = xb[g1]; b1 = xb[HW + g1]; }
    tile[0][0][l0] = a0; tile[0][1][l0] = b0;
    if (v1) { tile[0][0][l1] = a1; tile[0][1][l1] = b1; }
    {
        const float* xc = xb + 2 * HW;
        a0 = xc[g0]; b0 = xc[HW + g0];
        if (v1) { a1 = xc[g1]; b1 = xc[HW + g1]; }
    }
    __syncthreads();

    float acc[9];
#pragma unroll
    for (int k = 0; k < 9; ++k) acc[k] = 0.f;

    for (int e = 0; e < Cc / 2; ++e) {
        // write next pair's tile from regs (loads issued one full iteration ago)
        if (e + 1 < Cc / 2) {
            float* t0 = tile[(e + 1) & 1][0];
            float* t1 = tile[(e + 1) & 1][1];
            t0[l0] = a0; t1[l0] = b0;
            if (v1) { t0[l1] = a1; t1[l1] = b1; }
        }
        // issue loads for pair e+2
        if (e + 2 < Cc / 2) {
            const float* xc = xb + (size_t)(2 * (e + 2)) * HW;
            a0 = xc[g0]; b0 = xc[HW + g0];
            if (v1) { a1 = xc[g1]; b1 = xc[HW + g1]; }
        }
        // compute pair e
#pragma unroll
        for (int ch = 0; ch < 2; ++ch) {
            const float* tl = tile[e & 1][ch];
            float xv[9];
#pragma unroll
            for (int dy = 0; dy < 3; ++dy)
#pragma unroll
                for (int dx = 0; dx < 3; ++dx)
                    xv[dy * 3 + dx] = tl[(ty + dy) * TP + (tx + dx)];
            const int c = 2 * e + ch;
#pragma unroll
            for (int k = 0; k < 9; ++k) {
                const float* wk = wgt + ((size_t)k * Cc + c) * 9;
#pragma unroll
                for (int t = 0; t < 9; ++t)
                    acc[k] = fmaf(wk[t], xv[t], acc[k]);
            }
        }
        __syncthreads();
    }

    // raw sigma at even positions, tap-major layout [9][n][oh][ow]
    if (((ty & 1) == 0) && ((tx & 1) == 0)) {
        const int oh = (h0 + ty) >> 1, ow = (w0 + tx) >> 1;
        const int p = n * OP + oh * OWw + ow;
#pragma unroll
        for (int k = 0; k < 9; ++k) sig_raw[(size_t)k * NP + p] = acc[k];
    }

    // stats reduction
    const int lane = tid & 63;
    const int wv = tid >> 6;
#pragma unroll
    for (int k = 0; k < 9; ++k) {
        float s = acc[k];
        float q = acc[k] * acc[k];
#pragma unroll
        for (int off = 32; off > 0; off >>= 1) {
            s += __shfl_down(s, off, 64);
            q += __shfl_down(q, off, 64);
        }
        if (lane == 0) { red_sum[wv][k] = s; red_sq[wv][k] = q; }
    }
    __syncthreads();
    if (tid < 9) {
        const float s = red_sum[0][tid] + red_sum[1][tid] + red_sum[2][tid] + red_sum[3][tid];
        const float q = red_sq[0][tid] + red_sq[1][tid] + red_sq[2][tid] + red_sq[3][tid];
        atomicAdd(&stats[tid], (double)s);
        atomicAdd(&stats[9 + tid], (double)q);
    }
}

// ---------------- K1b: BN + clamp + tap-normalize once per position (tap-major in/out).
__global__ __launch_bounds__(256) void normalize_kernel(
    const float* __restrict__ sig_raw, const float* __restrict__ gamma,
    const float* __restrict__ beta, const double* __restrict__ stats,
    float* __restrict__ sig_norm /* [9][NP] */)
{
    __shared__ float mean_s[9], istd_s[9], gam_s[9], bet_s[9];
    const int tid = threadIdx.x;
    if (tid < 9) {
        const double cnt = (double)Nn * HW;
        const double m = stats[tid] / cnt;
        const double v = stats[9 + tid] / cnt - m * m;
        mean_s[tid] = (float)m;
        istd_s[tid] = (float)(1.0 / sqrt(v + (double)BN_EPS_F));
        gam_s[tid] = gamma[tid];
        bet_s[tid] = beta[tid];
    }
    __syncthreads();

    const int p = blockIdx.x * 256 + tid;   // NP = 196 * 256 exactly
    float s[9], ssum = 0.f;
#pragma unroll
    for (int k = 0; k < 9; ++k) {
        float v = fmaf((sig_raw[(size_t)k * NP + p] - mean_s[k]) * istd_s[k], gam_s[k], bet_s[k]);
        v = fmaxf(v, CLAMP_MIN_F);
        s[k] = v;
        ssum += v;
    }
    const float inv = 1.f / ssum;
#pragma unroll
    for (int k = 0; k < 9; ++k) sig_norm[(size_t)k * NP + p] = s[k] * inv;
}

// ---------------- K2: streaming apply — thread per output, 4 consecutive chunks/block.
__global__ __launch_bounds__(256) void apply_kernel(
    const float* __restrict__ x, const float* __restrict__ sig_norm,
    float* __restrict__ out)
{
    const int tid = threadIdx.x;
    const int base = blockIdx.x * 1024;
#pragma unroll
    for (int u = 0; u < 4; ++u) {
        const int p = base + u * 256 + tid;            // < 3,211,264
        const int ow = p % OWw;
        const int t1 = p / OWw;
        const int oh = t1 % OHh;
        const int nc = t1 / OHh;                       // n*64 + c
        const int n = nc >> 6;

        const float* xc = x + (size_t)nc * HW;
        const int sb = n * OP + oh * OWw + ow;

        const int r0 = (oh == 0) ? 1 : (2 * oh - 1);
        const int r1 = 2 * oh, r2 = 2 * oh + 1;
        const int c0 = (ow == 0) ? 1 : (2 * ow - 1);
        const int c1 = 2 * ow, c2 = 2 * ow + 1;

        float o = 0.f;
        o = fmaf(sig_norm[0 * NP + sb], xc[r0 * Ww + c0], o);
        o = fmaf(sig_norm[1 * NP + sb], xc[r0 * Ww + c1], o);
        o = fmaf(sig_norm[2 * NP + sb], xc[r0 * Ww + c2], o);
        o = fmaf(sig_norm[3 * NP + sb], xc[r1 * Ww + c0], o);
        o = fmaf(sig_norm[4 * NP + sb], xc[r1 * Ww + c1], o);
        o = fmaf(sig_norm[5 * NP + sb], xc[r1 * Ww + c2], o);
        o = fmaf(sig_norm[6 * NP + sb], xc[r2 * Ww + c0], o);
        o = fmaf(sig_norm[7 * NP + sb], xc[r2 * Ww + c1], o);
        o = fmaf(sig_norm[8 * NP + sb], xc[r2 * Ww + c2], o);
        out[p] = o;
    }
}

} // namespace

extern "C" void kernel_launch(void* const* d_in, const int* in_sizes, int n_in,
                              void* d_out, int out_size, void* d_ws, size_t ws_size,
                              hipStream_t stream) {
    const float* x     = (const float*)d_in[0];
    const float* wgt   = (const float*)d_in[1];
    const float* gamma = (const float*)d_in[2];
    const float* beta  = (const float*)d_in[3];
    float* out = (float*)d_out;

    double* stats   = (double*)d_ws;                                  // 18 doubles
    float* sig_raw  = (float*)((char*)d_ws + 256);                    // 9*NP floats
    float* sig_norm = (float*)((char*)d_ws + 256 + (size_t)9 * NP * 4);

    hipMemsetAsync(d_ws, 0, 256, stream);
    conv_stats_sig_kernel<<<dim3(49, 16), 256, 0, stream>>>(x, wgt, stats, sig_raw);
    normalize_kernel<<<NP / 256, 256, 0, stream>>>(sig_raw, gamma, beta, stats, sig_norm);
    apply_kernel<<<(Nn * Cc * OP) / 1024, 256, 0, stream>>>(x, sig_norm, out);
}